// Round 3
// baseline (1696.762 us; speedup 1.0000x reference)
//
#include <hip/hip_runtime.h>
#include <hip/hip_bf16.h>

#define T_STEPS 512
#define HID 512
#define EMB_D 300
#define BATCH 64
#define NCLS 1000

typedef __attribute__((ext_vector_type(4))) float f32x4;
typedef __attribute__((ext_vector_type(8))) short bf16x8;
typedef __attribute__((ext_vector_type(4))) unsigned int u32x4;
typedef __attribute__((ext_vector_type(2))) unsigned int u32x2;

union FragU { u32x4 u; bf16x8 b; };

__device__ __forceinline__ unsigned cvtpk(float lo, float hi) {
  unsigned r;
  asm("v_cvt_pk_bf16_f32 %0, %1, %2" : "=v"(r) : "v"(lo), "v"(hi));
  return r;
}

__device__ __forceinline__ bf16x8 pack8(f32x4 lo, f32x4 hi) {
  FragU u;
  u.u = (u32x4){cvtpk(lo.x, lo.y), cvtpk(lo.z, lo.w), cvtpk(hi.x, hi.y), cvtpk(hi.z, hi.w)};
  return u.b;
}

__device__ __forceinline__ float tanh_fast(float x) {
  // tanh(x) = (e-1)/(e+1), e = 2^(2*log2e*x). Clamp keeps exp2 finite; tanh(15)==1 in f32.
  x = fminf(15.0f, fmaxf(-15.0f, x));
  float e = __builtin_amdgcn_exp2f(x * 2.8853900817779268f);
  return (e - 1.0f) * __builtin_amdgcn_rcpf(e + 1.0f);
}

// ---------------------------------------------------------------------------
// K1: xp[t][n][b] (bf16) = emb[x[b,t]] . W_ih[n,:] + b_ih[n] + b_hh[n]
// One wave per (t, 16-col tile); 4 M-subtiles of 16 batch rows each (full b).
// K padded 300 -> 320 with masked (zero) loads; 16x16x32 bf16 MFMA.
// ---------------------------------------------------------------------------
__global__ __launch_bounds__(256) void k1_embed_proj(
    const int* __restrict__ x, const float* __restrict__ emb,
    const float* __restrict__ Wih, const float* __restrict__ bih,
    const float* __restrict__ bhh, unsigned short* __restrict__ xp) {
  const int tid = threadIdx.x;
  const int wid = blockIdx.x * 4 + (tid >> 6);   // 0..16383 = 512 t * 32 ntiles
  const int lane = tid & 63;
  const int c = lane & 15, g = lane >> 4;
  const int t = wid >> 5;
  const int n = ((wid & 31) << 4) + c;

  int xi[4];
  #pragma unroll
  for (int a = 0; a < 4; ++a) xi[a] = x[(a * 16 + c) * T_STEPS + t];

  f32x4 acc[4] = {{0,0,0,0},{0,0,0,0},{0,0,0,0},{0,0,0,0}};
  const f32x4 z4 = {0, 0, 0, 0};

  #pragma unroll
  for (int kk = 0; kk < 10; ++kk) {
    const int k0 = kk * 32 + g * 8;
    const bool mlo = (k0 < EMB_D);
    const bool mhi = (k0 + 4 < EMB_D);
    f32x4 blo = mlo ? *(const f32x4*)(Wih + (size_t)n * EMB_D + k0) : z4;
    f32x4 bhi = mhi ? *(const f32x4*)(Wih + (size_t)n * EMB_D + k0 + 4) : z4;
    bf16x8 bfrag = pack8(blo, bhi);
    #pragma unroll
    for (int a = 0; a < 4; ++a) {
      const float* arow = emb + (size_t)xi[a] * EMB_D;
      f32x4 alo = mlo ? *(const f32x4*)(arow + k0) : z4;
      f32x4 ahi = mhi ? *(const f32x4*)(arow + k0 + 4) : z4;
      acc[a] = __builtin_amdgcn_mfma_f32_16x16x32_bf16(pack8(alo, ahi), bfrag, acc[a], 0, 0, 0);
    }
  }

  const float bias = bih[n] + bhh[n];
  #pragma unroll
  for (int a = 0; a < 4; ++a) {
    f32x4 o = acc[a] + bias;
    u32x2 pk = { cvtpk(o.x, o.y), cvtpk(o.z, o.w) };
    const int b = a * 16 + g * 4;           // D rows (lane>>4)*4+reg -> batch index
    *(u32x2*)(xp + ((size_t)t * HID + n) * BATCH + b) = pk;
  }
}

// ---------------------------------------------------------------------------
// K2: persistent RNN. 4 WGs x 512 thr (8 waves). WG owns 16 batch rows, all 512
// cols. Wave owns 64 cols; W_hh slice weight-stationary: 49 frags in VGPRs,
// 15 frags in LDS. h double-buffered in LDS (bf16, stride 520 => aligned b128,
// ~2-way banks). One __syncthreads per step.
// ---------------------------------------------------------------------------
__global__ __launch_bounds__(512) void k2_rnn(
    const float* __restrict__ Whh, const unsigned short* __restrict__ xp,
    float* __restrict__ hT) {
  __shared__ unsigned short hbuf[2][16][520];     // 33,280 B
  __shared__ unsigned short wlds[8][15][512];     // 122,880 B

  const int tid = threadIdx.x;
  const int wv = tid >> 6;
  const int lane = tid & 63;
  const int c = lane & 15, g = lane >> 4;
  const int wg = blockIdx.x;                      // batch rows wg*16..wg*16+15
  const int n_wave = wv * 64;

  // ---- stage W_hh (bf16). B[k=j][n=i] = Whh[i][j]; frag: k0 = kk*32 + g*8 ----
  auto ldw = [&](int ntile, int kk) -> bf16x8 {
    const int i = n_wave + ntile * 16 + c;
    const int k0 = kk * 32 + g * 8;
    f32x4 lo = *(const f32x4*)(Whh + (size_t)i * HID + k0);
    f32x4 hi = *(const f32x4*)(Whh + (size_t)i * HID + k0 + 4);
    return pack8(lo, hi);
  };
  bf16x8 wr0[16], wr1[16], wr2[16], w30;
  #pragma unroll
  for (int kk = 0; kk < 16; ++kk) { wr0[kk] = ldw(0, kk); wr1[kk] = ldw(1, kk); wr2[kk] = ldw(2, kk); }
  w30 = ldw(3, 0);
  #pragma unroll
  for (int kk = 1; kk < 16; ++kk) {
    bf16x8 f = ldw(3, kk);
    *(bf16x8*)&wlds[wv][kk - 1][lane * 8] = f;
  }

  for (int i = tid; i < 2 * 16 * 520; i += 512) ((unsigned short*)hbuf)[i] = 0;  // h0 = 0
  __syncthreads();

  const unsigned short* xpp = xp + (size_t)(n_wave + c) * BATCH + wg * 16 + g * 4;
  int cur = 0;

  #pragma unroll 1
  for (int t = 0; t < T_STEPS; ++t) {
    // prefetch xp (bf16x4 per tau) early; consumed after the MFMA block
    u32x2 xq0 = *(const u32x2*)(xpp);
    u32x2 xq1 = *(const u32x2*)(xpp + 1024);
    u32x2 xq2 = *(const u32x2*)(xpp + 2048);
    u32x2 xq3 = *(const u32x2*)(xpp + 3072);

    f32x4 acc0 = {0,0,0,0}, acc1 = {0,0,0,0}, acc2 = {0,0,0,0}, acc3 = {0,0,0,0};
    const unsigned short* hb = &hbuf[cur][0][0];
    #pragma unroll
    for (int kk = 0; kk < 16; ++kk) {
      bf16x8 af = *(const bf16x8*)(hb + c * 520 + kk * 32 + g * 8);
      acc0 = __builtin_amdgcn_mfma_f32_16x16x32_bf16(af, wr0[kk], acc0, 0, 0, 0);
      acc1 = __builtin_amdgcn_mfma_f32_16x16x32_bf16(af, wr1[kk], acc1, 0, 0, 0);
      acc2 = __builtin_amdgcn_mfma_f32_16x16x32_bf16(af, wr2[kk], acc2, 0, 0, 0);
      bf16x8 w3 = (kk == 0) ? w30 : *(const bf16x8*)&wlds[wv][kk - 1][lane * 8];
      acc3 = __builtin_amdgcn_mfma_f32_16x16x32_bf16(af, w3, acc3, 0, 0, 0);
    }

    unsigned short* hw = &hbuf[cur ^ 1][g * 4][0];
    #pragma unroll
    for (int tau = 0; tau < 4; ++tau) {
      f32x4 a = (tau == 0) ? acc0 : (tau == 1) ? acc1 : (tau == 2) ? acc2 : acc3;
      u32x2 xq = (tau == 0) ? xq0 : (tau == 1) ? xq1 : (tau == 2) ? xq2 : xq3;
      float t0 = tanh_fast(a.x + __uint_as_float((xq.x & 0xffffu) << 16));
      float t1 = tanh_fast(a.y + __uint_as_float((xq.x >> 16) << 16));
      float t2 = tanh_fast(a.z + __uint_as_float((xq.y & 0xffffu) << 16));
      float t3 = tanh_fast(a.w + __uint_as_float((xq.y >> 16) << 16));
      unsigned u01 = cvtpk(t0, t1), u23 = cvtpk(t2, t3);
      const int n = n_wave + tau * 16 + c;
      hw[n]        = (unsigned short)(u01 & 0xffffu);
      hw[n + 520]  = (unsigned short)(u01 >> 16);
      hw[n + 1040] = (unsigned short)(u23 & 0xffffu);
      hw[n + 1560] = (unsigned short)(u23 >> 16);
      if (t == T_STEPS - 1) {
        float* o = hT + (size_t)(wg * 16 + g * 4) * HID + n;
        o[0] = t0; o[HID] = t1; o[2 * HID] = t2; o[3 * HID] = t3;
      }
    }
    __syncthreads();
    cur ^= 1;
    xpp += (size_t)HID * BATCH;
  }
}

// ---------------------------------------------------------------------------
// K3: out[b][c] = hT[b] . W_fc[c] + b_fc[c]
// ---------------------------------------------------------------------------
__global__ __launch_bounds__(256) void k3_head(
    const float* __restrict__ hT, const float* __restrict__ Wfc,
    const float* __restrict__ bfc, float* __restrict__ out) {
  __shared__ float hrow[HID];
  const int b = blockIdx.x, tid = threadIdx.x;
  hrow[tid] = hT[(size_t)b * HID + tid];
  hrow[tid + 256] = hT[(size_t)b * HID + tid + 256];
  __syncthreads();
  for (int cc = tid; cc < NCLS; cc += 256) {
    const f32x4* W4 = (const f32x4*)(Wfc + (size_t)cc * HID);
    float s0 = 0, s1 = 0, s2 = 0, s3 = 0;
    #pragma unroll 4
    for (int j = 0; j < HID / 4; ++j) {
      f32x4 w = W4[j];
      f32x4 h4 = *(const f32x4*)(hrow + j * 4);
      s0 += h4.x * w.x; s1 += h4.y * w.y; s2 += h4.z * w.z; s3 += h4.w * w.w;
    }
    out[(size_t)b * NCLS + cc] = bfc[cc] + s0 + s1 + s2 + s3;
  }
}

extern "C" void kernel_launch(void* const* d_in, const int* in_sizes, int n_in,
                              void* d_out, int out_size, void* d_ws, size_t ws_size,
                              hipStream_t stream) {
  (void)in_sizes; (void)n_in; (void)out_size; (void)ws_size;
  const int*   x   = (const int*)d_in[0];
  const float* emb = (const float*)d_in[1];
  const float* Wih = (const float*)d_in[2];
  const float* Whh = (const float*)d_in[3];
  const float* bih = (const float*)d_in[4];
  const float* bhh = (const float*)d_in[5];
  const float* Wfc = (const float*)d_in[6];
  const float* bfc = (const float*)d_in[7];
  float* out = (float*)d_out;

  // ws: xp bf16 [T][HID][B] = 33,554,432 B, then hT f32 [B][HID] = 131,072 B
  unsigned short* xp = (unsigned short*)d_ws;
  float* hT = (float*)((char*)d_ws + (size_t)T_STEPS * HID * BATCH * 2);

  k1_embed_proj<<<4096, 256, 0, stream>>>(x, emb, Wih, bih, bhh, xp);
  k2_rnn<<<4, 512, 0, stream>>>(Whh, xp, hT);
  k3_head<<<64, 256, 0, stream>>>(hT, Wfc, bfc, out);
}